// Round 1
// baseline (1139.093 us; speedup 1.0000x reference)
//
#include <hip/hip_runtime.h>
#include <hip/hip_bf16.h>

#define N_ROWS 16384
#define DIMS   10240
#define NCLS   128
#define SPLITS 4
#define DCHUNK (DIMS / SPLITS)   // 2560

typedef __bf16 bf16x8 __attribute__((ext_vector_type(8)));
typedef float  f32x4  __attribute__((ext_vector_type(4)));

// Kernel 0: convert am (fp32, exactly +/-1) -> bf16 (exact).
__global__ __launch_bounds__(256) void k_cvt_am(const float* __restrict__ am,
                                                __bf16* __restrict__ amb) {
    int i = (blockIdx.x * 256 + threadIdx.x) * 8;
    const float4* p = (const float4*)(am + i);
    float4 a = p[0], b = p[1];
    bf16x8 o;
    o[0] = (__bf16)a.x; o[1] = (__bf16)a.y; o[2] = (__bf16)a.z; o[3] = (__bf16)a.w;
    o[4] = (__bf16)b.x; o[5] = (__bf16)b.y; o[6] = (__bf16)b.z; o[7] = (__bf16)b.w;
    *(bf16x8*)(amb + i) = o;
}

// Kernel 1: partial sims via 3-way bf16-split MFMA.
// Block = 4 waves, each wave = 16 rows x 128 cols, D-chunk per blockIdx.y.
__global__ __launch_bounds__(256) void k_sims(const float* __restrict__ x,
                                              const __bf16* __restrict__ amb,
                                              float* __restrict__ part) {
    const int lane = threadIdx.x & 63;
    const int wave = threadIdx.x >> 6;
    const int ln15 = lane & 15;
    const int kgrp = lane >> 4;                 // 0..3
    const int rowBase = blockIdx.x * 64 + wave * 16;
    const int d0 = blockIdx.y * DCHUNK;

    const float*  xr = x   + (size_t)(rowBase + ln15) * DIMS + d0 + kgrp * 8;
    const __bf16* br = amb + (size_t)ln15 * DIMS + d0 + kgrp * 8;

    f32x4 acc[8];
    #pragma unroll
    for (int t = 0; t < 8; ++t) acc[t] = (f32x4)0.0f;

    for (int kk = 0; kk < DCHUNK; kk += 32) {
        // A: 8 consecutive fp32, split into hi/mid/lo bf16 (exact 3-term decomposition)
        float xv[8];
        *(float4*)&xv[0] = *(const float4*)(xr + kk);
        *(float4*)&xv[4] = *(const float4*)(xr + kk + 4);
        bf16x8 hi, mi, lo;
        #pragma unroll
        for (int j = 0; j < 8; ++j) {
            float f  = xv[j];
            __bf16 h = (__bf16)f;
            float r1 = f - (float)h;      // exact
            __bf16 m = (__bf16)r1;
            float r2 = r1 - (float)m;     // exact
            hi[j] = h; mi[j] = m; lo[j] = (__bf16)r2;
        }
        #pragma unroll
        for (int t = 0; t < 8; ++t) {
            bf16x8 b = *(const bf16x8*)(br + (size_t)t * 16 * DIMS + kk);
            acc[t] = __builtin_amdgcn_mfma_f32_16x16x32_bf16(hi, b, acc[t], 0, 0, 0);
            acc[t] = __builtin_amdgcn_mfma_f32_16x16x32_bf16(mi, b, acc[t], 0, 0, 0);
            acc[t] = __builtin_amdgcn_mfma_f32_16x16x32_bf16(lo, b, acc[t], 0, 0, 0);
        }
    }

    // C/D layout (m89): col = lane&15, row = (lane>>4)*4 + j
    float* po = part + ((size_t)blockIdx.y * N_ROWS + rowBase + kgrp * 4) * NCLS + ln15;
    #pragma unroll
    for (int t = 0; t < 8; ++t) {
        #pragma unroll
        for (int j = 0; j < 4; ++j) {
            po[(size_t)j * NCLS + t * 16] = acc[t][j];
        }
    }
}

// Kernel 2: sum the SPLITS partials and argmax (first-max tie-break) per row.
// One wave per row; lane l covers classes l and l+64.
__global__ __launch_bounds__(256) void k_argmax(const float* __restrict__ part,
                                                int* __restrict__ preds) {
    int row = blockIdx.x * 4 + (threadIdx.x >> 6);
    int l = threadIdx.x & 63;
    const float* p = part + (size_t)row * NCLS;
    const size_t SS = (size_t)N_ROWS * NCLS;
    float s0 = 0.f, s1 = 0.f;
    #pragma unroll
    for (int s = 0; s < SPLITS; ++s) {
        s0 += p[(size_t)s * SS + l];
        s1 += p[(size_t)s * SS + l + 64];
    }
    float bv = s0; int bi = l;
    if (s1 > bv) { bv = s1; bi = l + 64; }       // tie keeps smaller idx
    #pragma unroll
    for (int off = 32; off >= 1; off >>= 1) {
        float ov = __shfl_xor(bv, off);
        int   oi = __shfl_xor(bi, off);
        if (ov > bv || (ov == bv && oi < bi)) { bv = ov; bi = oi; }
    }
    if (l == 0) preds[row] = bi;
}

extern "C" void kernel_launch(void* const* d_in, const int* in_sizes, int n_in,
                              void* d_out, int out_size, void* d_ws, size_t ws_size,
                              hipStream_t stream) {
    const float* x  = (const float*)d_in[0];
    const float* am = (const float*)d_in[1];

    __bf16* amb = (__bf16*)d_ws;
    float*  part = (float*)((char*)d_ws + (size_t)NCLS * DIMS * sizeof(__bf16));
    int*    preds = (int*)d_out;

    k_cvt_am<<<dim3((NCLS * DIMS) / (256 * 8)), 256, 0, stream>>>(am, amb);
    k_sims<<<dim3(N_ROWS / 64, SPLITS), 256, 0, stream>>>(x, amb, part);
    k_argmax<<<dim3(N_ROWS / 4), 256, 0, stream>>>(part, preds);
}